// Round 3
// baseline (719.868 us; speedup 1.0000x reference)
//
#include <hip/hip_runtime.h>
#include <hip/hip_bf16.h>

// GAT layer, B=8 N=4096 F=128 U=64, ALL I/O float32.
// out = relu( softmax_row( lrelu(s_i + t_j) masked by A ) @ X ),  X = H@W.
// R7: attn was stuck at ~1.6 TB/s on the A stream: the R6 loop drained
// vmcnt to 0 every chunk (ds_write of reg-staged data + __syncthreads), so
// avg outstanding bytes ~0.6 MB chip-wide vs the 2.36 MB Little's-law need.
// Fix = T3/T4 2-phase: global_load_lds staging (A, XT, t), raw s_barrier +
// counted s_waitcnt vmcnt(7) so next chunk's loads fly during compute; LDS
// bank conflicts fixed by XOR-swizzling the GLOBAL source (linear LDS dest)
// and the ds_read address (rule #21): 16-way -> 2-way (free).

#define NTOK 4096
#define FDIM 128
#define UDIM 64
#define BATCH 8
#define BK 64
#define NCHUNK (NTOK / BK)

typedef __attribute__((ext_vector_type(8))) short short8;
typedef __attribute__((ext_vector_type(4))) float f32x4;

union PackU { unsigned u[4]; short8 s; };

// round-to-nearest-even f32 -> bf16 (used in prep only)
__device__ __forceinline__ unsigned short f2bf(float x) {
    unsigned u = __float_as_uint(x);
    return (unsigned short)((u + 0x7fffu + ((u >> 16) & 1u)) >> 16);
}

__device__ __forceinline__ void gl2lds16(const void* g, void* l) {
    __builtin_amdgcn_global_load_lds(
        (const __attribute__((address_space(1))) unsigned int*)g,
        (__attribute__((address_space(3))) unsigned int*)l, 16, 0, 0);
}
__device__ __forceinline__ void gl2lds4(const void* g, void* l) {
    __builtin_amdgcn_global_load_lds(
        (const __attribute__((address_space(1))) unsigned int*)g,
        (__attribute__((address_space(3))) unsigned int*)l, 4, 0, 0);
}

// ---------------- kernel 1: X = H@W (MFMA), s,t (pre-scaled by log2e) ------
__global__ __launch_bounds__(256) void prep_kernel(
    const float* __restrict__ H,    // f32 [B*N, 128]
    const float* __restrict__ W,    // f32 [128, 64]
    const float* __restrict__ a1,   // f32 [64]
    const float* __restrict__ a2,   // f32 [64]
    unsigned short* __restrict__ XT,// bf16 [B, 64, N] (scratch)
    float* __restrict__ s_out,      // f32 [B*N], = (X@a1)*log2(e)
    float* __restrict__ t_out)      // f32 [B*N], = (X@a2)*log2(e)
{
    __shared__ float Xl[4][16][UDIM + 1];

    const int tid  = threadIdx.x;
    const int wave = tid >> 6, lane = tid & 63;
    const int col  = lane & 15, quad = lane >> 4;
    const int i0   = (blockIdx.x * 4 + wave) * 16;

    f32x4 acc0 = {0,0,0,0}, acc1 = {0,0,0,0}, acc2 = {0,0,0,0}, acc3 = {0,0,0,0};
    const float* hrow = H + (size_t)(i0 + col) * FDIM + quad * 8;

    #pragma unroll
    for (int kb = 0; kb < FDIM; kb += 32) {
        f32x4 h0 = *(const f32x4*)(hrow + kb);
        f32x4 h1 = *(const f32x4*)(hrow + kb + 4);
        short8 afr, b0, b1, b2, b3;
        #pragma unroll
        for (int j = 0; j < 4; ++j) {
            afr[j]     = (short)f2bf(h0[j]);
            afr[4 + j] = (short)f2bf(h1[j]);
        }
        #pragma unroll
        for (int j = 0; j < 8; ++j) {                // W tiny, L1-hot
            int k = kb + quad * 8 + j;
            b0[j] = (short)f2bf(W[k * UDIM + col]);
            b1[j] = (short)f2bf(W[k * UDIM + 16 + col]);
            b2[j] = (short)f2bf(W[k * UDIM + 32 + col]);
            b3[j] = (short)f2bf(W[k * UDIM + 48 + col]);
        }
        acc0 = __builtin_amdgcn_mfma_f32_16x16x32_bf16(afr, b0, acc0, 0, 0, 0);
        acc1 = __builtin_amdgcn_mfma_f32_16x16x32_bf16(afr, b1, acc1, 0, 0, 0);
        acc2 = __builtin_amdgcn_mfma_f32_16x16x32_bf16(afr, b2, acc2, 0, 0, 0);
        acc3 = __builtin_amdgcn_mfma_f32_16x16x32_bf16(afr, b3, acc3, 0, 0, 0);
    }
    #pragma unroll
    for (int r = 0; r < 4; ++r) {   // C/D: col(u)=lane&15 (+16/group), row=quad*4+r
        Xl[wave][quad * 4 + r][col]      = acc0[r];
        Xl[wave][quad * 4 + r][16 + col] = acc1[r];
        Xl[wave][quad * 4 + r][32 + col] = acc2[r];
        Xl[wave][quad * 4 + r][48 + col] = acc3[r];
    }
    __syncthreads();

    const int b = i0 >> 12, n0 = i0 & (NTOK - 1);
    float ps = 0.f, pt = 0.f;
    #pragma unroll
    for (int ui = 0; ui < 16; ++ui) {
        int u = quad * 16 + ui;
        float x = Xl[wave][col][u];
        ps = fmaf(x, a1[u], ps);
        pt = fmaf(x, a2[u], pt);
    }
    ps += __shfl_xor(ps, 16, 64); ps += __shfl_xor(ps, 32, 64);
    pt += __shfl_xor(pt, 16, 64); pt += __shfl_xor(pt, 32, 64);
    const float LOG2E = 1.44269504f;
    if (quad == 0) s_out[i0 + col] = ps * LOG2E;   // exp2 domain
    if (quad == 1) t_out[i0 + col] = pt * LOG2E;

    #pragma unroll
    for (int ui = 0; ui < 16; ++ui) {
        int u = quad * 16 + ui;
        XT[(size_t)(b * UDIM + u) * NTOK + n0 + col] = f2bf(Xl[wave][col][u]);
    }
}

// ---------------- kernel 2: fused mask+softmax+PV ---------------------------
// grid 512 = 8 batches x 64 row-tiles-of-64, 4 waves/block; wave w owns rows
// w*16..w*16+15 across full K. Per chunk (BK=64): As [64][64] f32 (16 KB),
// Xs [64][64] bf16 (8 KB), Ts [4][64] f32, all via global_load_lds into
// linear LDS, XOR-swizzled on the source side; 2 raw barriers/chunk, vmcnt
// held at 7 (next chunk's loads) -- never drained in the main loop.
__global__ __launch_bounds__(256) void attn_kernel(
    const float* __restrict__ A,            // f32 [B, N, N] -- 512 MB stream
    const unsigned short* __restrict__ XT,  // bf16 [B, 64, N]
    const float* __restrict__ s_in,         // log2e-scaled
    const float* __restrict__ t_in,         // log2e-scaled
    float* __restrict__ out)                // f32 [B, N, 64]
{
    __shared__ __align__(16) float          As[2][64 * BK];  // 32 KB
    __shared__ __align__(16) unsigned short Xs[2][64 * BK];  // 16 KB
    __shared__ __align__(16) float          Ts[2][4][BK];    //  2 KB

    const int tid  = threadIdx.x;
    const int wave = tid >> 6, lane = tid & 63;
    const int col  = lane & 15, quad = lane >> 4;
    const int b    = blockIdx.x & 7;
    const int i0   = (blockIdx.x >> 3) * 64;

    // --- staging source pointers (per-lane, pre-swizzled; LDS dest linear) ---
    // A instr j: lane l -> row r = wave*16 + j*4 + (l>>4), 16B-block v = (l&15)^(r&7)
    const float* agp[4];
    #pragma unroll
    for (int j = 0; j < 4; ++j) {
        int r = wave * 16 + j * 4 + (lane >> 4);
        int v = (lane & 15) ^ (r & 7);
        agp[j] = A + ((size_t)(b * NTOK + i0 + r)) * NTOK + v * 4;
    }
    // X instr j: lane l -> u = wave*16 + j*8 + (l>>3), block v = (l&7)^(u&7)
    const unsigned short* xgp[2];
    #pragma unroll
    for (int j = 0; j < 2; ++j) {
        int u = wave * 16 + j * 8 + (lane >> 3);
        int v = (lane & 7) ^ (u & 7);
        xgp[j] = XT + ((size_t)(b * UDIM + u)) * NTOK + v * 8;
    }
    const float* tgp = t_in + b * NTOK + lane;

    const float s_m = s_in[b * NTOK + i0 + wave * 16 + col];

    f32x4 acc[4];
    #pragma unroll
    for (int f = 0; f < 4; ++f) acc[f] = (f32x4){0,0,0,0};
    float den = 0.f;

    // 7 gloads per wave per chunk: 4 A + 2 X + 1 T
    #define STAGE(bufi, cc) do {                                              \
        gl2lds16(agp[0] + (cc) * BK, (void*)&As[bufi][(wave * 4 + 0) * 256]); \
        gl2lds16(agp[1] + (cc) * BK, (void*)&As[bufi][(wave * 4 + 1) * 256]); \
        gl2lds16(agp[2] + (cc) * BK, (void*)&As[bufi][(wave * 4 + 2) * 256]); \
        gl2lds16(agp[3] + (cc) * BK, (void*)&As[bufi][(wave * 4 + 3) * 256]); \
        gl2lds16(xgp[0] + (cc) * BK, (void*)&Xs[bufi][(wave * 2 + 0) * 512]); \
        gl2lds16(xgp[1] + (cc) * BK, (void*)&Xs[bufi][(wave * 2 + 1) * 512]); \
        gl2lds4 (tgp    + (cc) * BK, (void*)&Ts[bufi][wave][0]);              \
    } while (0)

    // prologue: chunk 0
    STAGE(0, 0);
    asm volatile("s_waitcnt vmcnt(0)" ::: "memory");
    __builtin_amdgcn_s_barrier();
    __builtin_amdgcn_sched_barrier(0);

    #pragma unroll 2
    for (int c = 0; c < NCHUNK; ++c) {
        const int buf = c & 1;
        if (c + 1 < NCHUNK) {
            STAGE(buf ^ 1, c + 1);
            asm volatile("s_waitcnt vmcnt(7)" ::: "memory");  // chunk c landed; c+1 in flight
        } else {
            asm volatile("s_waitcnt vmcnt(0)" ::: "memory");
        }
        __builtin_amdgcn_sched_barrier(0);
        __builtin_amdgcn_s_barrier();        // all waves: chunk c fully in LDS
        __builtin_amdgcn_sched_barrier(0);

        const int R   = wave * 16 + col;     // this lane's token row
        const int xsw = col & 7;             // Xs row-XOR (same for all 4 frags)
        #pragma unroll
        for (int ks = 0; ks < 2; ++ks) {
            const int v0 = 8 * ks + 2 * quad;
            f32x4 a0 = *(const f32x4*)&As[buf][R * 64 + ((v0)     ^ (R & 7)) * 4];
            f32x4 a1 = *(const f32x4*)&As[buf][R * 64 + ((v0 + 1) ^ (R & 7)) * 4];
            f32x4 t0 = *(const f32x4*)&Ts[buf][wave][ks * 32 + quad * 8];
            f32x4 t1 = *(const f32x4*)&Ts[buf][wave][ks * 32 + quad * 8 + 4];

            unsigned uw[8];
            #pragma unroll
            for (int j = 0; j < 4; ++j) {
                float l0 = s_m + t0[j], l1 = s_m + t1[j];
                float e0 = fmaxf(l0, 0.2f * l0);   // lrelu commutes with log2e>0
                float e1 = fmaxf(l1, 0.2f * l1);
                float w0 = __builtin_amdgcn_exp2f(e0) * a0[j];  // masked -> exact 0
                float w1 = __builtin_amdgcn_exp2f(e1) * a1[j];
                den += w0 + w1;
                uw[j]     = __float_as_uint(w0) + 0x8000u;  // round-half-up bf16
                uw[4 + j] = __float_as_uint(w1) + 0x8000u;
            }
            PackU p;   // pack hi16 pairs: afr[k]=w(k), k=quad*8+j
            p.u[0] = __builtin_amdgcn_perm(uw[1], uw[0], 0x07060302u);
            p.u[1] = __builtin_amdgcn_perm(uw[3], uw[2], 0x07060302u);
            p.u[2] = __builtin_amdgcn_perm(uw[5], uw[4], 0x07060302u);
            p.u[3] = __builtin_amdgcn_perm(uw[7], uw[6], 0x07060302u);

            const int xv = (4 * ks + quad) ^ xsw;
            short8 bf0 = *(const short8*)&Xs[buf][(col)      * 64 + xv * 8];
            short8 bf1 = *(const short8*)&Xs[buf][(16 + col) * 64 + xv * 8];
            short8 bf2 = *(const short8*)&Xs[buf][(32 + col) * 64 + xv * 8];
            short8 bf3 = *(const short8*)&Xs[buf][(48 + col) * 64 + xv * 8];

            acc[0] = __builtin_amdgcn_mfma_f32_16x16x32_bf16(p.s, bf0, acc[0], 0, 0, 0);
            acc[1] = __builtin_amdgcn_mfma_f32_16x16x32_bf16(p.s, bf1, acc[1], 0, 0, 0);
            acc[2] = __builtin_amdgcn_mfma_f32_16x16x32_bf16(p.s, bf2, acc[2], 0, 0, 0);
            acc[3] = __builtin_amdgcn_mfma_f32_16x16x32_bf16(p.s, bf3, acc[3], 0, 0, 0);
        }
        __builtin_amdgcn_sched_barrier(0);
        __builtin_amdgcn_s_barrier();        // reads of buf done before c+1 overwrites it
        __builtin_amdgcn_sched_barrier(0);
    }
    #undef STAGE

    // epilogue: den at lanes keyed by col; gather, divide, relu, store
    den += __shfl_xor(den, 16, 64);
    den += __shfl_xor(den, 32, 64);
    #pragma unroll
    for (int r = 0; r < 4; ++r) {
        float dd = __shfl(den, quad * 4 + r, 64);     // den of D-row quad*4+r
        const int row = i0 + wave * 16 + quad * 4 + r;
        #pragma unroll
        for (int f = 0; f < 4; ++f) {
            float o = fmaxf(acc[f][r] / dd, 0.f);
            __builtin_nontemporal_store(o, &out[(size_t)(b * NTOK + row) * UDIM + f * 16 + col]);
        }
    }
}

extern "C" void kernel_launch(void* const* d_in, const int* in_sizes, int n_in,
                              void* d_out, int out_size, void* d_ws, size_t ws_size,
                              hipStream_t stream) {
    const float* H  = (const float*)d_in[0];
    const float* A  = (const float*)d_in[1];
    const float* W  = (const float*)d_in[2];
    const float* a1 = (const float*)d_in[3];
    const float* a2 = (const float*)d_in[4];
    float* out = (float*)d_out;

    char* ws = (char*)d_ws;
    unsigned short* XT = (unsigned short*)ws;                               // 4 MB bf16
    size_t off = (size_t)BATCH * UDIM * NTOK * 2;
    float* s = (float*)(ws + off);                                          // 128 KB
    off += (size_t)BATCH * NTOK * 4;
    float* t = (float*)(ws + off);                                          // 128 KB

    prep_kernel<<<512, 256, 0, stream>>>(H, W, a1, a2, XT, s, t);
    attn_kernel<<<512, 256, 0, stream>>>(A, XT, s, t, out);
}

// Round 4
// 702.440 us; speedup vs baseline: 1.0248x; 1.0248x over previous
//
#include <hip/hip_runtime.h>
#include <hip/hip_bf16.h>

// GAT layer, B=8 N=4096 F=128 U=64, ALL I/O float32.
// out = relu( softmax_row( lrelu(s_i + t_j) masked by A ) @ X ),  X = H@W.
// R8 = revert to R6 (best measured, 707.4 us). Evidence across R4-R7: the
// timed region carries TWO ~300us 2-GiB harness fills (fill _ords form two
// residue classes per iteration); our kernels total ~90-120us vs a ~87us
// HBM floor (A=512MB dominates). All structural attn variants (scatter,
// byte-mask, reg-staged LDS, counted-vmcnt async) measured within fill
// noise of each other -> A streams at ~5-6 TB/s in all of them. R6 is the
// best-measured configuration; later "improvements" were noise or worse.

#define NTOK 4096
#define FDIM 128
#define UDIM 64
#define BATCH 8
#define BK 64          // k-chunk staged per barrier (2 MFMA k-steps)

typedef __attribute__((ext_vector_type(8))) short short8;
typedef __attribute__((ext_vector_type(4))) float f32x4;

union PackU { unsigned u[4]; short8 s; };

// round-to-nearest-even f32 -> bf16 (used in prep only)
__device__ __forceinline__ unsigned short f2bf(float x) {
    unsigned u = __float_as_uint(x);
    return (unsigned short)((u + 0x7fffu + ((u >> 16) & 1u)) >> 16);
}

// ---------------- kernel 1: X = H@W (MFMA), s,t (pre-scaled by log2e) ------
__global__ __launch_bounds__(256) void prep_kernel(
    const float* __restrict__ H,    // f32 [B*N, 128]
    const float* __restrict__ W,    // f32 [128, 64]
    const float* __restrict__ a1,   // f32 [64]
    const float* __restrict__ a2,   // f32 [64]
    unsigned short* __restrict__ XT,// bf16 [B, 64, N] (scratch)
    float* __restrict__ s_out,      // f32 [B*N], = (X@a1)*log2(e)
    float* __restrict__ t_out)      // f32 [B*N], = (X@a2)*log2(e)
{
    __shared__ float Xl[4][16][UDIM + 1];

    const int tid  = threadIdx.x;
    const int wave = tid >> 6, lane = tid & 63;
    const int col  = lane & 15, quad = lane >> 4;
    const int i0   = (blockIdx.x * 4 + wave) * 16;

    f32x4 acc0 = {0,0,0,0}, acc1 = {0,0,0,0}, acc2 = {0,0,0,0}, acc3 = {0,0,0,0};
    const float* hrow = H + (size_t)(i0 + col) * FDIM + quad * 8;

    #pragma unroll
    for (int kb = 0; kb < FDIM; kb += 32) {
        f32x4 h0 = *(const f32x4*)(hrow + kb);       // A[m=lane&15][k=quad*8+j]
        f32x4 h1 = *(const f32x4*)(hrow + kb + 4);
        short8 afr, b0, b1, b2, b3;
        #pragma unroll
        for (int j = 0; j < 4; ++j) {
            afr[j]     = (short)f2bf(h0[j]);
            afr[4 + j] = (short)f2bf(h1[j]);
        }
        #pragma unroll
        for (int j = 0; j < 8; ++j) {                // W tiny, L1-hot
            int k = kb + quad * 8 + j;
            b0[j] = (short)f2bf(W[k * UDIM + col]);
            b1[j] = (short)f2bf(W[k * UDIM + 16 + col]);
            b2[j] = (short)f2bf(W[k * UDIM + 32 + col]);
            b3[j] = (short)f2bf(W[k * UDIM + 48 + col]);
        }
        acc0 = __builtin_amdgcn_mfma_f32_16x16x32_bf16(afr, b0, acc0, 0, 0, 0);
        acc1 = __builtin_amdgcn_mfma_f32_16x16x32_bf16(afr, b1, acc1, 0, 0, 0);
        acc2 = __builtin_amdgcn_mfma_f32_16x16x32_bf16(afr, b2, acc2, 0, 0, 0);
        acc3 = __builtin_amdgcn_mfma_f32_16x16x32_bf16(afr, b3, acc3, 0, 0, 0);
    }
    #pragma unroll
    for (int r = 0; r < 4; ++r) {   // C/D: col(u)=lane&15 (+16/group), row=quad*4+r
        Xl[wave][quad * 4 + r][col]      = acc0[r];
        Xl[wave][quad * 4 + r][16 + col] = acc1[r];
        Xl[wave][quad * 4 + r][32 + col] = acc2[r];
        Xl[wave][quad * 4 + r][48 + col] = acc3[r];
    }
    __syncthreads();

    const int b = i0 >> 12, n0 = i0 & (NTOK - 1);
    float ps = 0.f, pt = 0.f;
    #pragma unroll
    for (int ui = 0; ui < 16; ++ui) {
        int u = quad * 16 + ui;
        float x = Xl[wave][col][u];
        ps = fmaf(x, a1[u], ps);
        pt = fmaf(x, a2[u], pt);
    }
    ps += __shfl_xor(ps, 16, 64); ps += __shfl_xor(ps, 32, 64);
    pt += __shfl_xor(pt, 16, 64); pt += __shfl_xor(pt, 32, 64);
    const float LOG2E = 1.44269504f;
    if (quad == 0) s_out[i0 + col] = ps * LOG2E;   // exp2 domain
    if (quad == 1) t_out[i0 + col] = pt * LOG2E;

    #pragma unroll
    for (int ui = 0; ui < 16; ++ui) {
        int u = quad * 16 + ui;
        XT[(size_t)(b * UDIM + u) * NTOK + n0 + col] = f2bf(Xl[wave][col][u]);
    }
}

// ---------------- kernel 2: fused mask+softmax+PV ---------------------------
// grid 512 = 8 batches x 64 row-tiles-of-64 (b = bx&7), 4 waves/block.
// Wave w owns rows [i0+w*16, +16) across the FULL k range. A[64][BK] f32 and
// XT[64][BK] bf16 staged per chunk via coalesced block-cooperative loads into
// double-buffered padded LDS; one __syncthreads per chunk.
__global__ __launch_bounds__(256) void attn_kernel(
    const float* __restrict__ A,            // f32 [B, N, N] -- 512 MB stream
    const unsigned short* __restrict__ XT,  // bf16 [B, 64, N]
    const float* __restrict__ s_in,         // log2e-scaled
    const float* __restrict__ t_in,         // log2e-scaled
    float* __restrict__ out)                // f32 [B, N, 64]
{
    __shared__ __align__(16) float          As[2][64][BK + 4];  // 34.8 KB
    __shared__ __align__(16) unsigned short Xs[2][64][BK + 8];  // 18.4 KB

    const int tid  = threadIdx.x;
    const int wave = tid >> 6, lane = tid & 63;
    const int col  = lane & 15, quad = lane >> 4;
    const int b    = blockIdx.x & 7;
    const int i0   = (blockIdx.x >> 3) * 64;

    // staging assignment: A -> 4 instrs, each 16 rows x 256 B (4x256B segs/wave)
    //                     XT -> 2 instrs, each 32 rows x 128 B
    const int arow = tid >> 4, acol = (tid & 15) * 4;
    const int xrow = tid >> 3, xcol = (tid & 7) * 8;
    const float* agp = A + ((size_t)(b * NTOK + i0 + arow)) * NTOK + acol;
    const unsigned short* xgp = XT + ((size_t)(b * UDIM + xrow)) * NTOK + xcol;

    const float s_m = s_in[b * NTOK + i0 + wave * 16 + col];
    const float* tbase = t_in + b * NTOK;

    f32x4 acc[4];
    #pragma unroll
    for (int f = 0; f < 4; ++f) acc[f] = (f32x4){0,0,0,0};
    float den = 0.f;

    f32x4 av[4], xv[2];

    // prologue: stage chunk 0
    #pragma unroll
    for (int i = 0; i < 4; ++i)
        av[i] = __builtin_nontemporal_load((const f32x4*)(agp + (size_t)i * 16 * NTOK));
    #pragma unroll
    for (int i = 0; i < 2; ++i)
        xv[i] = *(const f32x4*)(xgp + (size_t)i * 32 * NTOK);
    #pragma unroll
    for (int i = 0; i < 4; ++i) *(f32x4*)&As[0][arow + i * 16][acol] = av[i];
    #pragma unroll
    for (int i = 0; i < 2; ++i) *(f32x4*)&Xs[0][xrow + i * 32][xcol] = xv[i];

    for (int c = 0; c < NTOK / BK; ++c) {
        const int buf = c & 1;
        if (c < NTOK / BK - 1) {         // issue next-chunk loads (land under compute)
            const float* ag = agp + (c + 1) * BK;
            const unsigned short* xg = xgp + (c + 1) * BK;
            #pragma unroll
            for (int i = 0; i < 4; ++i)
                av[i] = __builtin_nontemporal_load((const f32x4*)(ag + (size_t)i * 16 * NTOK));
            #pragma unroll
            for (int i = 0; i < 2; ++i)
                xv[i] = *(const f32x4*)(xg + (size_t)i * 32 * NTOK);
        }
        __syncthreads();                 // buf's ds_writes visible; prev reads done

        #pragma unroll
        for (int ks = 0; ks < 2; ++ks) {
            const float* ar = &As[buf][wave * 16 + col][ks * 32 + quad * 8];
            f32x4 a0 = *(const f32x4*)ar;
            f32x4 a1 = *(const f32x4*)(ar + 4);
            const float* tp = tbase + c * BK + ks * 32 + quad * 8;
            f32x4 t0 = *(const f32x4*)tp;
            f32x4 t1 = *(const f32x4*)(tp + 4);

            unsigned uw[8];
            #pragma unroll
            for (int j = 0; j < 4; ++j) {
                float l0 = s_m + t0[j], l1 = s_m + t1[j];
                float e0 = fmaxf(l0, 0.2f * l0);   // lrelu commutes with log2e>0
                float e1 = fmaxf(l1, 0.2f * l1);
                float w0 = __builtin_amdgcn_exp2f(e0) * a0[j];  // masked -> exact 0
                float w1 = __builtin_amdgcn_exp2f(e1) * a1[j];
                den += w0 + w1;
                uw[j]     = __float_as_uint(w0) + 0x8000u;  // round-half-up bf16
                uw[4 + j] = __float_as_uint(w1) + 0x8000u;
            }
            PackU p;   // pack hi16 pairs: afr[k]=w(k), k=quad*8+j
            p.u[0] = __builtin_amdgcn_perm(uw[1], uw[0], 0x07060302u);
            p.u[1] = __builtin_amdgcn_perm(uw[3], uw[2], 0x07060302u);
            p.u[2] = __builtin_amdgcn_perm(uw[5], uw[4], 0x07060302u);
            p.u[3] = __builtin_amdgcn_perm(uw[7], uw[6], 0x07060302u);

            short8 bf0 = *(const short8*)&Xs[buf][col]     [ks * 32 + quad * 8];
            short8 bf1 = *(const short8*)&Xs[buf][16 + col][ks * 32 + quad * 8];
            short8 bf2 = *(const short8*)&Xs[buf][32 + col][ks * 32 + quad * 8];
            short8 bf3 = *(const short8*)&Xs[buf][48 + col][ks * 32 + quad * 8];

            acc[0] = __builtin_amdgcn_mfma_f32_16x16x32_bf16(p.s, bf0, acc[0], 0, 0, 0);
            acc[1] = __builtin_amdgcn_mfma_f32_16x16x32_bf16(p.s, bf1, acc[1], 0, 0, 0);
            acc[2] = __builtin_amdgcn_mfma_f32_16x16x32_bf16(p.s, bf2, acc[2], 0, 0, 0);
            acc[3] = __builtin_amdgcn_mfma_f32_16x16x32_bf16(p.s, bf3, acc[3], 0, 0, 0);
        }

        if (c < NTOK / BK - 1) {         // write next chunk into the other buffer
            const int nb = buf ^ 1;
            #pragma unroll
            for (int i = 0; i < 4; ++i) *(f32x4*)&As[nb][arow + i * 16][acol] = av[i];
            #pragma unroll
            for (int i = 0; i < 2; ++i) *(f32x4*)&Xs[nb][xrow + i * 32][xcol] = xv[i];
        }
    }

    // epilogue: den lives at lane with col==row; gather, divide, relu, store
    den += __shfl_xor(den, 16, 64);
    den += __shfl_xor(den, 32, 64);      // full row-den at every quad, keyed by col
    #pragma unroll
    for (int r = 0; r < 4; ++r) {
        float dd = __shfl(den, quad * 4 + r, 64);     // den of D-row quad*4+r
        const int row = i0 + wave * 16 + quad * 4 + r;
        #pragma unroll
        for (int f = 0; f < 4; ++f) {
            float o = fmaxf(acc[f][r] / dd, 0.f);
            __builtin_nontemporal_store(o, &out[(size_t)(b * NTOK + row) * UDIM + f * 16 + col]);
        }
    }
}

extern "C" void kernel_launch(void* const* d_in, const int* in_sizes, int n_in,
                              void* d_out, int out_size, void* d_ws, size_t ws_size,
                              hipStream_t stream) {
    const float* H  = (const float*)d_in[0];
    const float* A  = (const float*)d_in[1];
    const float* W  = (const float*)d_in[2];
    const float* a1 = (const float*)d_in[3];
    const float* a2 = (const float*)d_in[4];
    float* out = (float*)d_out;

    char* ws = (char*)d_ws;
    unsigned short* XT = (unsigned short*)ws;                               // 4 MB bf16
    size_t off = (size_t)BATCH * UDIM * NTOK * 2;
    float* s = (float*)(ws + off);                                          // 128 KB
    off += (size_t)BATCH * NTOK * 4;
    float* t = (float*)(ws + off);                                          // 128 KB

    prep_kernel<<<512, 256, 0, stream>>>(H, W, a1, a2, XT, s, t);
    attn_kernel<<<512, 256, 0, stream>>>(A, XT, s, t, out);
}